// Round 1
// baseline (370.414 us; speedup 1.0000x reference)
//
#include <hip/hip_runtime.h>
#include <hip/hip_bf16.h>

#define CDIM 128
#define EDIM 16
#define NEG_SLOPE 0.2f

// ---------------- flag kernel: classify dtype of `reducible` buffer ----------------
// flags[0]=notInt, flags[1]=notFloat
__global__ void flag_kernel(const unsigned int* __restrict__ red, int nwords, int* __restrict__ flags) {
    int i = blockIdx.x * 256 + threadIdx.x;
    if (i >= nwords) return;
    unsigned int w = red[i];
    bool isInt = (w <= 1u);
    bool isFloat = (w == 0u) || (w == 0x3f800000u);
    if (!isInt) atomicOr(&flags[0], 1);
    if (!isFloat) atomicOr(&flags[1], 1);
}

// ---------------- build Bcat = [W_r | W_i | W_res_r | W_res_i]  [128][512] ----------------
__global__ void bcat_kernel(const float* __restrict__ Wr, const float* __restrict__ Wi,
                            const float* __restrict__ Wrr, const float* __restrict__ Wri,
                            float* __restrict__ B) {
    int idx = blockIdx.x * 256 + threadIdx.x;
    if (idx >= 128 * 512) return;
    int k = idx >> 9, c = idx & 511;
    float v;
    if (c < 128)      v = Wr [k * 128 + c];
    else if (c < 256) v = Wi [k * 128 + (c - 128)];
    else if (c < 384) v = Wrr[k * 128 + (c - 256)];
    else              v = Wri[k * 128 + (c - 384)];
    B[idx] = v;
}

// ---------------- w_e = W_edge @ att_edge  (16 scalars per variant) ----------------
__global__ void we_kernel(const float* __restrict__ WeR, const float* __restrict__ aeR,
                          const float* __restrict__ WeI, const float* __restrict__ aeI,
                          float* __restrict__ we) {
    int lane = threadIdx.x;
    if (lane < 16) {
        float s = 0.f;
        for (int c = 0; c < CDIM; ++c) s += WeR[lane * CDIM + c] * aeR[c];
        we[lane] = s;
    } else if (lane < 32) {
        int j = lane - 16;
        float s = 0.f;
        for (int c = 0; c < CDIM; ++c) s += WeI[j * CDIM + c] * aeI[c];
        we[16 + j] = s;
    }
}

// ---------------- GEMM: xcat[N][512] = h[N][128] @ Bcat[128][512] ----------------
__global__ __launch_bounds__(256) void gemm_kernel(const float* __restrict__ A,
                                                   const float* __restrict__ B,
                                                   float* __restrict__ C, int M) {
    __shared__ float As[32][132];
    __shared__ float Bs[32][132];
    int t = threadIdx.x;
    int rb = blockIdx.x * 128;
    int cb = blockIdx.y * 128;
    int tx = t & 15, ty = t >> 4;
    float acc[2][2][4][4];
#pragma unroll
    for (int a = 0; a < 2; ++a)
#pragma unroll
        for (int b = 0; b < 2; ++b)
#pragma unroll
            for (int i = 0; i < 4; ++i)
#pragma unroll
                for (int j = 0; j < 4; ++j) acc[a][b][i][j] = 0.f;

    for (int k0 = 0; k0 < 128; k0 += 32) {
        // A tile 128x32 (store transposed As[k][m])
#pragma unroll
        for (int p = 0; p < 4; ++p) {
            int row = (t >> 3) + p * 32;
            int kc  = (t & 7) * 4;
            int gr  = rb + row;
            float4 v = make_float4(0.f, 0.f, 0.f, 0.f);
            if (gr < M) v = *(const float4*)&A[(size_t)gr * 128 + k0 + kc];
            As[kc + 0][row] = v.x; As[kc + 1][row] = v.y;
            As[kc + 2][row] = v.z; As[kc + 3][row] = v.w;
        }
        // B tile 32x128
#pragma unroll
        for (int p = 0; p < 4; ++p) {
            int kr  = (t >> 5) + p * 8;
            int col = (t & 31) * 4;
            float4 v = *(const float4*)&B[(size_t)(k0 + kr) * 512 + cb + col];
            *(float4*)&Bs[kr][col] = v;
        }
        __syncthreads();
#pragma unroll
        for (int kk = 0; kk < 32; ++kk) {
            float4 a0 = *(const float4*)&As[kk][ty * 4];
            float4 a1 = *(const float4*)&As[kk][ty * 4 + 64];
            float4 b0 = *(const float4*)&Bs[kk][tx * 4];
            float4 b1 = *(const float4*)&Bs[kk][tx * 4 + 64];
            float ar[2][4] = {{a0.x, a0.y, a0.z, a0.w}, {a1.x, a1.y, a1.z, a1.w}};
            float br[2][4] = {{b0.x, b0.y, b0.z, b0.w}, {b1.x, b1.y, b1.z, b1.w}};
#pragma unroll
            for (int rg = 0; rg < 2; ++rg)
#pragma unroll
                for (int cg = 0; cg < 2; ++cg)
#pragma unroll
                    for (int i = 0; i < 4; ++i)
#pragma unroll
                        for (int j = 0; j < 4; ++j)
                            acc[rg][cg][i][j] += ar[rg][i] * br[cg][j];
        }
        __syncthreads();
    }
#pragma unroll
    for (int rg = 0; rg < 2; ++rg)
#pragma unroll
        for (int i = 0; i < 4; ++i) {
            int row = rb + ty * 4 + rg * 64 + i;
            if (row < M) {
#pragma unroll
                for (int cg = 0; cg < 2; ++cg) {
                    float4 v = make_float4(acc[rg][cg][i][0], acc[rg][cg][i][1],
                                           acc[rg][cg][i][2], acc[rg][cg][i][3]);
                    *(float4*)&C[(size_t)row * 512 + cb + tx * 4 + cg * 64] = v;
                }
            }
        }
}

// ---------------- per-node attention dots: a_src/a_dst for both variants ----------------
__global__ __launch_bounds__(256) void adots_kernel(const float* __restrict__ xcat,
                                                    const float* __restrict__ attsr, const float* __restrict__ attdr,
                                                    const float* __restrict__ attsi, const float* __restrict__ attdi,
                                                    float* __restrict__ asr, float* __restrict__ adr,
                                                    float* __restrict__ asi, float* __restrict__ adi, int n) {
    int node = blockIdx.x * 4 + (threadIdx.x >> 6);
    int lane = threadIdx.x & 63;
    if (node >= n) return;
    const float2* xr = (const float2*)(xcat + (size_t)node * 512);
    const float2* xi = xr + 64;
    float2 vr = xr[lane], vi = xi[lane];
    float2 sr = ((const float2*)attsr)[lane], dr = ((const float2*)attdr)[lane];
    float2 si = ((const float2*)attsi)[lane], di = ((const float2*)attdi)[lane];
    float s0 = vr.x * sr.x + vr.y * sr.y;
    float s1 = vr.x * dr.x + vr.y * dr.y;
    float s2 = vi.x * si.x + vi.y * si.y;
    float s3 = vi.x * di.x + vi.y * di.y;
#pragma unroll
    for (int d = 32; d; d >>= 1) {
        s0 += __shfl_xor(s0, d); s1 += __shfl_xor(s1, d);
        s2 += __shfl_xor(s2, d); s3 += __shfl_xor(s3, d);
    }
    if (lane == 0) { asr[node] = s0; adr[node] = s1; asi[node] = s2; adi[node] = s3; }
}

// ---------------- histogram of in-degree ----------------
__global__ void hist_kernel(const int* __restrict__ dst, int* __restrict__ cnt, int E) {
    int e = blockIdx.x * 256 + threadIdx.x;
    if (e < E) atomicAdd(&cnt[dst[e]], 1);
}

// ---------------- exclusive scan (single block, chunked) ----------------
__global__ __launch_bounds__(1024) void scan_kernel(const int* __restrict__ cnt, int* __restrict__ offv,
                                                    int* __restrict__ cursor, int n) {
    __shared__ int wsum[16];
    __shared__ int s_carry;
    int t = threadIdx.x, lane = t & 63, wid = t >> 6;
    if (t == 0) s_carry = 0;
    __syncthreads();
    for (int base = 0; base < n; base += 4096) {
        int i0 = base + t * 4;
        int v[4];
#pragma unroll
        for (int j = 0; j < 4; ++j) { int i = i0 + j; v[j] = (i < n) ? cnt[i] : 0; }
        int s = v[0] + v[1] + v[2] + v[3];
        int incl = s;
#pragma unroll
        for (int d = 1; d < 64; d <<= 1) { int u = __shfl_up(incl, d); if (lane >= d) incl += u; }
        if (lane == 63) wsum[wid] = incl;
        __syncthreads();
        int carry = s_carry;
        int wpre = 0;
        for (int w = 0; w < wid; ++w) wpre += wsum[w];
        int run = carry + wpre + (incl - s);
#pragma unroll
        for (int j = 0; j < 4; ++j) {
            int i = i0 + j;
            if (i < n) { offv[i] = run; cursor[i] = run; }
            run += v[j];
        }
        __syncthreads();
        if (t == 1023) s_carry = carry + wpre + incl;
        __syncthreads();
    }
    if (t == 0) offv[n] = s_carry;
}

// ---------------- edge pass: e-scalars + scatter into CSR ----------------
__global__ void scatter_kernel(const int* __restrict__ src, const int* __restrict__ dst,
                               const float* __restrict__ ea, const float* __restrict__ we,
                               int* __restrict__ cursor, int* __restrict__ src_s,
                               float* __restrict__ er_s, float* __restrict__ ei_s, int E) {
    int e = blockIdx.x * 256 + threadIdx.x;
    if (e >= E) return;
    int s = src[e], d = dst[e];
    const float4* row = (const float4*)(ea + (size_t)e * EDIM);
    float er = 0.f, ei = 0.f;
#pragma unroll
    for (int q = 0; q < 4; ++q) {
        float4 v = row[q];
        float4 wr = ((const float4*)we)[q];
        float4 wi = ((const float4*)we)[4 + q];
        er += v.x * wr.x + v.y * wr.y + v.z * wr.z + v.w * wr.w;
        ei += v.x * wi.x + v.y * wi.y + v.z * wi.z + v.w * wi.w;
    }
    int pos = atomicAdd(&cursor[d], 1);
    src_s[pos] = s;
    er_s[pos] = er;
    ei_s[pos] = ei;
}

// ---------------- node kernel: online softmax + weighted gather + residual + select + relu ----------------
__global__ __launch_bounds__(256) void node_kernel(
    const float* __restrict__ xcat,
    const float* __restrict__ asrc_r, const float* __restrict__ adst_r,
    const float* __restrict__ asrc_i, const float* __restrict__ adst_i,
    const void* __restrict__ red, const int* __restrict__ flags,
    const int* __restrict__ offv, const int* __restrict__ src_s,
    const float* __restrict__ er_s, const float* __restrict__ ei_s,
    const float* __restrict__ bias_r, const float* __restrict__ bias_i,
    float* __restrict__ out, int n) {
    int node = blockIdx.x * 4 + (threadIdx.x >> 6);
    int lane = threadIdx.x & 63;
    if (node >= n) return;

    int notInt = flags[0], notFloat = flags[1];
    bool r;
    if (!notInt)        r = ((const int*)red)[node] != 0;
    else if (!notFloat) r = ((const float*)red)[node] != 0.f;
    else                r = ((const unsigned char*)red)[node] != 0;

    const float* asrc = r ? asrc_r : asrc_i;
    float adst = (r ? adst_r : adst_i)[node];
    const float* er = r ? er_s : ei_s;
    const float* xv = xcat + (r ? 0 : 128);

    int b0 = offv[node], b1 = offv[node + 1];
    int k = b1 - b0;

    float m = -1e30f, denom = 0.f;
    float acc0 = 0.f, acc1 = 0.f;
    float sumE = 0.f;

    for (int base = b0; base < b1; base += 64) {
        int j = base + lane;
        int s = 0; float alpha = -1e30f;
        if (j < b1) {
            s = src_s[j];
            float e = er[j];
            sumE += e;
            float a = asrc[s] + adst + e;
            alpha = (a >= 0.f) ? a : NEG_SLOPE * a;
        }
        float cm = alpha;
#pragma unroll
        for (int d = 32; d; d >>= 1) cm = fmaxf(cm, __shfl_xor(cm, d));
        float mn = fmaxf(m, cm);
        float scale = __expf(m - mn);
        denom *= scale; acc0 *= scale; acc1 *= scale;
        m = mn;
        float ex = (j < b1) ? __expf(alpha - mn) : 0.f;
        float exs = ex;
#pragma unroll
        for (int d = 32; d; d >>= 1) exs += __shfl_xor(exs, d);
        denom += exs;
        int cc = min(64, b1 - base);
        for (int t = 0; t < cc; ++t) {
            float w = __shfl(ex, t);
            int ss = __shfl(s, t);
            float2 v = ((const float2*)(xv + (size_t)ss * 512))[lane];
            acc0 += w * v.x; acc1 += w * v.y;
        }
    }
    // self loop
#pragma unroll
    for (int d = 32; d; d >>= 1) sumE += __shfl_xor(sumE, d);
    float eself = sumE / fmaxf((float)k, 1.f);
    float a = asrc[node] + adst + eself;
    float aself = (a >= 0.f) ? a : NEG_SLOPE * a;
    float mn = fmaxf(m, aself);
    float sc = __expf(m - mn);
    float exl = __expf(aself - mn);
    denom = denom * sc + exl;
    float2 vs = ((const float2*)(xv + (size_t)node * 512))[lane];
    acc0 = acc0 * sc + exl * vs.x;
    acc1 = acc1 * sc + exl * vs.y;

    float inv = 1.f / denom;
    const float* basev = xcat + (size_t)node * 512 + (r ? 256 : 384);
    const float* biasv = r ? bias_r : bias_i;
    float2 bb = ((const float2*)basev)[lane];
    float2 bi2 = ((const float2*)biasv)[lane];
    float o0 = acc0 * inv + bb.x + bi2.x;
    float o1 = acc1 * inv + bb.y + bi2.y;
    out[(size_t)node * 128 + lane * 2]     = fmaxf(o0, 0.f);
    out[(size_t)node * 128 + lane * 2 + 1] = fmaxf(o1, 0.f);
}

extern "C" void kernel_launch(void* const* d_in, const int* in_sizes, int n_in,
                              void* d_out, int out_size, void* d_ws, size_t ws_size,
                              hipStream_t stream) {
    const float* h          = (const float*)d_in[0];
    const int*   edge_index = (const int*)d_in[1];
    const float* edge_attr  = (const float*)d_in[2];
    const void*  reducible  = d_in[3];
    const float* red_W      = (const float*)d_in[4];
    const float* red_att_src= (const float*)d_in[5];
    const float* red_att_dst= (const float*)d_in[6];
    const float* red_W_edge = (const float*)d_in[7];
    const float* red_att_edge=(const float*)d_in[8];
    const float* red_W_res  = (const float*)d_in[9];
    const float* red_bias   = (const float*)d_in[10];
    const float* irr_W      = (const float*)d_in[11];
    const float* irr_att_src= (const float*)d_in[12];
    const float* irr_att_dst= (const float*)d_in[13];
    const float* irr_W_edge = (const float*)d_in[14];
    const float* irr_att_edge=(const float*)d_in[15];
    const float* irr_W_res  = (const float*)d_in[16];
    const float* irr_bias   = (const float*)d_in[17];

    const int N = in_sizes[0] / CDIM;
    const int E = in_sizes[1] / 2;
    const int* src = edge_index;
    const int* dst = edge_index + E;

    float* out = (float*)d_out;

    // workspace layout
    size_t cur = 0;
    auto alloc = [&](size_t bytes) { size_t p = cur; cur = (cur + bytes + 255) & ~(size_t)255; return p; };
    char* ws = (char*)d_ws;
    size_t o_xcat  = alloc((size_t)N * 512 * 4);
    size_t o_bcat  = alloc(128 * 512 * 4);
    size_t o_we    = alloc(256);
    size_t o_asr   = alloc((size_t)N * 4);
    size_t o_adr   = alloc((size_t)N * 4);
    size_t o_asi   = alloc((size_t)N * 4);
    size_t o_adi   = alloc((size_t)N * 4);
    size_t o_flags = alloc(256);
    size_t o_cnt   = alloc((size_t)N * 4);
    size_t o_off   = alloc((size_t)(N + 1) * 4);
    size_t o_cur   = alloc((size_t)N * 4);
    size_t o_srcs  = alloc((size_t)E * 4);
    size_t o_ers   = alloc((size_t)E * 4);
    size_t o_eis   = alloc((size_t)E * 4);
    if (cur > ws_size) return;  // workspace too small: fail visibly (output stays poisoned)

    float* xcat  = (float*)(ws + o_xcat);
    float* bcat  = (float*)(ws + o_bcat);
    float* we    = (float*)(ws + o_we);
    float* asr   = (float*)(ws + o_asr);
    float* adr   = (float*)(ws + o_adr);
    float* asi   = (float*)(ws + o_asi);
    float* adi   = (float*)(ws + o_adi);
    int*   flags = (int*)(ws + o_flags);
    int*   cnt   = (int*)(ws + o_cnt);
    int*   offv  = (int*)(ws + o_off);
    int*   curs  = (int*)(ws + o_cur);
    int*   src_s = (int*)(ws + o_srcs);
    float* er_s  = (float*)(ws + o_ers);
    float* ei_s  = (float*)(ws + o_eis);

    hipMemsetAsync(flags, 0, 8, stream);
    hipMemsetAsync(cnt, 0, (size_t)N * 4, stream);

    int nwords = N / 4;  // safe in all dtype interpretations
    flag_kernel<<<(nwords + 255) / 256, 256, 0, stream>>>((const unsigned int*)reducible, nwords, flags);

    bcat_kernel<<<(128 * 512 + 255) / 256, 256, 0, stream>>>(red_W, irr_W, red_W_res, irr_W_res, bcat);
    we_kernel<<<1, 32, 0, stream>>>(red_W_edge, red_att_edge, irr_W_edge, irr_att_edge, we);

    dim3 ggrid((N + 127) / 128, 4);
    gemm_kernel<<<ggrid, 256, 0, stream>>>(h, bcat, xcat, N);

    adots_kernel<<<(N + 3) / 4, 256, 0, stream>>>(xcat, red_att_src, red_att_dst,
                                                  irr_att_src, irr_att_dst, asr, adr, asi, adi, N);

    hist_kernel<<<(E + 255) / 256, 256, 0, stream>>>(dst, cnt, E);
    scan_kernel<<<1, 1024, 0, stream>>>(cnt, offv, curs, N);
    scatter_kernel<<<(E + 255) / 256, 256, 0, stream>>>(src, dst, edge_attr, we, curs,
                                                        src_s, er_s, ei_s, E);

    node_kernel<<<(N + 3) / 4, 256, 0, stream>>>(xcat, asr, adr, asi, adi,
                                                 reducible, flags, offv, src_s, er_s, ei_s,
                                                 red_bias, irr_bias, out, N);
}

// Round 2
// 257.782 us; speedup vs baseline: 1.4369x; 1.4369x over previous
//
#include <hip/hip_runtime.h>
#include <hip/hip_bf16.h>

#define CDIM 128
#define EDIM 16
#define NEG_SLOPE 0.2f

typedef __attribute__((ext_vector_type(8))) short bf16x8;
typedef __attribute__((ext_vector_type(4))) float f32x4;
typedef unsigned int uint;
typedef unsigned short ushort;

__device__ __forceinline__ ushort f2bf(float f) {
    uint u = __float_as_uint(f);
    return (ushort)((u + 0x7fffu + ((u >> 16) & 1u)) >> 16);
}
__device__ __forceinline__ float bflo(uint w) { return __uint_as_float(w << 16); }
__device__ __forceinline__ float bfhi(uint w) { return __uint_as_float(w & 0xffff0000u); }

// ---------------- flag kernel: classify dtype of `reducible` buffer ----------------
__global__ void flag_kernel(const uint* __restrict__ red, int nwords, int* __restrict__ flags) {
    int i = blockIdx.x * 256 + threadIdx.x;
    if (i >= nwords) return;
    uint w = red[i];
    bool isInt = (w <= 1u);
    bool isFloat = (w == 0u) || (w == 0x3f800000u);
    if (!isInt) atomicOr(&flags[0], 1);
    if (!isFloat) atomicOr(&flags[1], 1);
}

// ---------------- h -> bf16 ----------------
__global__ void hconv_kernel(const float* __restrict__ h, ushort* __restrict__ hbf, int n4) {
    int i = blockIdx.x * 256 + threadIdx.x;
    if (i >= n4) return;
    float4 v = ((const float4*)h)[i];
    ushort4 o;
    o.x = f2bf(v.x); o.y = f2bf(v.y); o.z = f2bf(v.z); o.w = f2bf(v.w);
    ((ushort4*)hbf)[i] = o;
}

// ---------------- BcatT[c][k] = W?[k][c&127] (bf16, transposed) ----------------
// col layout: 0-127 x_r, 128-255 x_i, 256-383 res_r, 384-511 res_i
__global__ void bcat_kernel(const float* __restrict__ Wr, const float* __restrict__ Wi,
                            const float* __restrict__ Wrr, const float* __restrict__ Wri,
                            ushort* __restrict__ BT) {
    int idx = blockIdx.x * 256 + threadIdx.x;
    if (idx >= 512 * 128) return;
    int c = idx >> 7, k = idx & 127;
    const float* srcm;
    if (c < 128)      srcm = Wr;
    else if (c < 256) srcm = Wi;
    else if (c < 384) srcm = Wrr;
    else              srcm = Wri;
    BT[idx] = f2bf(srcm[k * 128 + (c & 127)]);
}

// ---------------- w_e = W_edge @ att_edge  (16 scalars per variant) ----------------
__global__ void we_kernel(const float* __restrict__ WeR, const float* __restrict__ aeR,
                          const float* __restrict__ WeI, const float* __restrict__ aeI,
                          float* __restrict__ we) {
    int lane = threadIdx.x;
    if (lane < 16) {
        float s = 0.f;
        for (int c = 0; c < CDIM; ++c) s += WeR[lane * CDIM + c] * aeR[c];
        we[lane] = s;
    } else if (lane < 32) {
        int j = lane - 16;
        float s = 0.f;
        for (int c = 0; c < CDIM; ++c) s += WeI[j * CDIM + c] * aeI[c];
        we[16 + j] = s;
    }
}

// ---------------- MFMA GEMM: xcat[M][512](bf16) = hbf[M][128] @ Bcat ----------------
// A,BT bf16; K=128 in one LDS tile; 4 waves 2x2; per wave 64x64 out = 4x4 frags 16x16x32.
__global__ __launch_bounds__(256) void gemm_mfma(const ushort* __restrict__ A,
                                                 const ushort* __restrict__ BT,
                                                 ushort* __restrict__ C, int M) {
    __shared__ ushort As[128 * 128];
    __shared__ ushort Bs[128 * 128];
    int t = threadIdx.x;
    int lane = t & 63, wv = t >> 6;
    int rb = blockIdx.x * 128, cb = blockIdx.y * 128;

    // stage A[128][128] and BT-slab[128][128] into LDS, pre-swizzled source chunk
    int rsub = wv * 4 + (lane >> 4);   // 0..15 within each 16-row group
    int c0 = lane & 15;
#pragma unroll
    for (int p = 0; p < 8; ++p) {
        int row = p * 16 + rsub;       // 0..127
        int chunk = c0 ^ (row & 7);
        int gra = rb + row; if (gra > M - 1) gra = M - 1;
        const ushort* ga = A + (size_t)gra * 128 + chunk * 8;
        __builtin_amdgcn_global_load_lds(
            (const __attribute__((address_space(1))) void*)ga,
            (__attribute__((address_space(3))) void*)((char*)As + p * 4096 + wv * 1024),
            16, 0, 0);
        const ushort* gb = BT + (size_t)(cb + row) * 128 + chunk * 8;
        __builtin_amdgcn_global_load_lds(
            (const __attribute__((address_space(1))) void*)gb,
            (__attribute__((address_space(3))) void*)((char*)Bs + p * 4096 + wv * 1024),
            16, 0, 0);
    }
    __syncthreads();

    int wr = wv >> 1, wc = wv & 1;
    int l15 = lane & 15, l4 = lane >> 4;
    f32x4 acc[4][4];
#pragma unroll
    for (int i = 0; i < 4; ++i)
#pragma unroll
        for (int j = 0; j < 4; ++j) acc[i][j] = (f32x4){0.f, 0.f, 0.f, 0.f};

    const char* Ab = (const char*)As;
    const char* Bb = (const char*)Bs;
#pragma unroll
    for (int ks = 0; ks < 4; ++ks) {
        bf16x8 a[4], b[4];
#pragma unroll
        for (int f = 0; f < 4; ++f) {
            int row = wr * 64 + f * 16 + l15;
            int ch = (ks * 4 + l4) ^ (row & 7);
            a[f] = *(const bf16x8*)(Ab + row * 256 + ch * 16);
            int col = wc * 64 + f * 16 + l15;
            int ch2 = (ks * 4 + l4) ^ (col & 7);
            b[f] = *(const bf16x8*)(Bb + col * 256 + ch2 * 16);
        }
#pragma unroll
        for (int i = 0; i < 4; ++i)
#pragma unroll
            for (int j = 0; j < 4; ++j)
                acc[i][j] = __builtin_amdgcn_mfma_f32_16x16x32_bf16(a[i], b[j], acc[i][j], 0, 0, 0);
    }

    // epilogue: D lane layout col=l&15, row=(l>>4)*4+reg
#pragma unroll
    for (int i = 0; i < 4; ++i) {
        int rl = wr * 64 + i * 16 + l4 * 4;
#pragma unroll
        for (int j = 0; j < 4; ++j) {
            int col = cb + wc * 64 + j * 16 + l15;
#pragma unroll
            for (int r = 0; r < 4; ++r) {
                int gr = rb + rl + r;
                if (gr < M) C[(size_t)gr * 512 + col] = f2bf(acc[i][j][r]);
            }
        }
    }
}

// ---------------- per-node attention dots (xcat is bf16) ----------------
__global__ __launch_bounds__(256) void adots_kernel(const ushort* __restrict__ xcat,
                                                    const float* __restrict__ attsr, const float* __restrict__ attdr,
                                                    const float* __restrict__ attsi, const float* __restrict__ attdi,
                                                    float* __restrict__ asr, float* __restrict__ adr,
                                                    float* __restrict__ asi, float* __restrict__ adi, int n) {
    int node = blockIdx.x * 4 + (threadIdx.x >> 6);
    int lane = threadIdx.x & 63;
    if (node >= n) return;
    const uint* xr = (const uint*)(xcat + (size_t)node * 512);
    uint wr_ = xr[lane];        // x_r cols 2l, 2l+1
    uint wi_ = xr[64 + lane];   // x_i
    float r0 = bflo(wr_), r1 = bfhi(wr_);
    float i0 = bflo(wi_), i1 = bfhi(wi_);
    float2 sr = ((const float2*)attsr)[lane], dr = ((const float2*)attdr)[lane];
    float2 si = ((const float2*)attsi)[lane], di = ((const float2*)attdi)[lane];
    float s0 = r0 * sr.x + r1 * sr.y;
    float s1 = r0 * dr.x + r1 * dr.y;
    float s2 = i0 * si.x + i1 * si.y;
    float s3 = i0 * di.x + i1 * di.y;
#pragma unroll
    for (int d = 32; d; d >>= 1) {
        s0 += __shfl_xor(s0, d); s1 += __shfl_xor(s1, d);
        s2 += __shfl_xor(s2, d); s3 += __shfl_xor(s3, d);
    }
    if (lane == 0) { asr[node] = s0; adr[node] = s1; asi[node] = s2; adi[node] = s3; }
}

// ---------------- histogram of in-degree ----------------
__global__ void hist_kernel(const int* __restrict__ dst, int* __restrict__ cnt, int E) {
    int e = blockIdx.x * 256 + threadIdx.x;
    if (e < E) atomicAdd(&cnt[dst[e]], 1);
}

// ---------------- exclusive scan (single block, chunked) ----------------
__global__ __launch_bounds__(1024) void scan_kernel(const int* __restrict__ cnt, int* __restrict__ offv,
                                                    int* __restrict__ cursor, int n) {
    __shared__ int wsum[16];
    __shared__ int s_carry;
    int t = threadIdx.x, lane = t & 63, wid = t >> 6;
    if (t == 0) s_carry = 0;
    __syncthreads();
    for (int base = 0; base < n; base += 4096) {
        int i0 = base + t * 4;
        int v[4];
#pragma unroll
        for (int j = 0; j < 4; ++j) { int i = i0 + j; v[j] = (i < n) ? cnt[i] : 0; }
        int s = v[0] + v[1] + v[2] + v[3];
        int incl = s;
#pragma unroll
        for (int d = 1; d < 64; d <<= 1) { int u = __shfl_up(incl, d); if (lane >= d) incl += u; }
        if (lane == 63) wsum[wid] = incl;
        __syncthreads();
        int carry = s_carry;
        int wpre = 0;
        for (int w = 0; w < wid; ++w) wpre += wsum[w];
        int run = carry + wpre + (incl - s);
#pragma unroll
        for (int j = 0; j < 4; ++j) {
            int i = i0 + j;
            if (i < n) { offv[i] = run; cursor[i] = run; }
            run += v[j];
        }
        __syncthreads();
        if (t == 1023) s_carry = carry + wpre + incl;
        __syncthreads();
    }
    if (t == 0) offv[n] = s_carry;
}

// ---------------- edge pass: e-scalars + scatter into CSR ----------------
__global__ void scatter_kernel(const int* __restrict__ src, const int* __restrict__ dst,
                               const float* __restrict__ ea, const float* __restrict__ we,
                               int* __restrict__ cursor, int* __restrict__ src_s,
                               float* __restrict__ er_s, float* __restrict__ ei_s, int E) {
    int e = blockIdx.x * 256 + threadIdx.x;
    if (e >= E) return;
    int s = src[e], d = dst[e];
    const float4* row = (const float4*)(ea + (size_t)e * EDIM);
    float er = 0.f, ei = 0.f;
#pragma unroll
    for (int q = 0; q < 4; ++q) {
        float4 v = row[q];
        float4 wr = ((const float4*)we)[q];
        float4 wi = ((const float4*)we)[4 + q];
        er += v.x * wr.x + v.y * wr.y + v.z * wr.z + v.w * wr.w;
        ei += v.x * wi.x + v.y * wi.y + v.z * wi.z + v.w * wi.w;
    }
    int pos = atomicAdd(&cursor[d], 1);
    src_s[pos] = s;
    er_s[pos] = er;
    ei_s[pos] = ei;
}

// ---------------- node kernel: online softmax + gather + residual + select + relu ----------------
__global__ __launch_bounds__(256) void node_kernel(
    const ushort* __restrict__ xcat,
    const float* __restrict__ asrc_r, const float* __restrict__ adst_r,
    const float* __restrict__ asrc_i, const float* __restrict__ adst_i,
    const void* __restrict__ red, const int* __restrict__ flags,
    const int* __restrict__ offv, const int* __restrict__ src_s,
    const float* __restrict__ er_s, const float* __restrict__ ei_s,
    const float* __restrict__ bias_r, const float* __restrict__ bias_i,
    float* __restrict__ out, int n) {
    int node = blockIdx.x * 4 + (threadIdx.x >> 6);
    int lane = threadIdx.x & 63;
    if (node >= n) return;

    int notInt = flags[0], notFloat = flags[1];
    bool r;
    if (!notInt)        r = ((const int*)red)[node] != 0;
    else if (!notFloat) r = ((const float*)red)[node] != 0.f;
    else                r = ((const unsigned char*)red)[node] != 0;

    const float* asrc = r ? asrc_r : asrc_i;
    float adst = (r ? adst_r : adst_i)[node];
    const float* er = r ? er_s : ei_s;
    const ushort* xv = xcat + (r ? 0 : 128);

    int b0 = offv[node], b1 = offv[node + 1];
    int k = b1 - b0;

    float m = -1e30f, denom = 0.f;
    float acc0 = 0.f, acc1 = 0.f;
    float sumE = 0.f;

    for (int base = b0; base < b1; base += 64) {
        int j = base + lane;
        int s = 0; float alpha = -1e30f;
        if (j < b1) {
            s = src_s[j];
            float e = er[j];
            sumE += e;
            float a = asrc[s] + adst + e;
            alpha = (a >= 0.f) ? a : NEG_SLOPE * a;
        }
        float cm = alpha;
#pragma unroll
        for (int d = 32; d; d >>= 1) cm = fmaxf(cm, __shfl_xor(cm, d));
        float mn = fmaxf(m, cm);
        float scale = __expf(m - mn);
        denom *= scale; acc0 *= scale; acc1 *= scale;
        m = mn;
        float ex = (j < b1) ? __expf(alpha - mn) : 0.f;
        float exs = ex;
#pragma unroll
        for (int d = 32; d; d >>= 1) exs += __shfl_xor(exs, d);
        denom += exs;
        int cc = min(64, b1 - base);
        for (int t = 0; t < cc; ++t) {
            float w = __shfl(ex, t);
            int ss = __shfl(s, t);
            uint v = ((const uint*)(xv + (size_t)ss * 512))[lane];
            acc0 += w * bflo(v); acc1 += w * bfhi(v);
        }
    }
    // self loop
#pragma unroll
    for (int d = 32; d; d >>= 1) sumE += __shfl_xor(sumE, d);
    float eself = sumE / fmaxf((float)k, 1.f);
    float a = asrc[node] + adst + eself;
    float aself = (a >= 0.f) ? a : NEG_SLOPE * a;
    float mn = fmaxf(m, aself);
    float sc = __expf(m - mn);
    float exl = __expf(aself - mn);
    denom = denom * sc + exl;
    uint vsw = ((const uint*)(xv + (size_t)node * 512))[lane];
    acc0 = acc0 * sc + exl * bflo(vsw);
    acc1 = acc1 * sc + exl * bfhi(vsw);

    float inv = 1.f / denom;
    const ushort* basev = xcat + (size_t)node * 512 + (r ? 256 : 384);
    const float* biasv = r ? bias_r : bias_i;
    uint bw = ((const uint*)basev)[lane];
    float2 bi2 = ((const float2*)biasv)[lane];
    float o0 = acc0 * inv + bflo(bw) + bi2.x;
    float o1 = acc1 * inv + bfhi(bw) + bi2.y;
    out[(size_t)node * 128 + lane * 2]     = fmaxf(o0, 0.f);
    out[(size_t)node * 128 + lane * 2 + 1] = fmaxf(o1, 0.f);
}

extern "C" void kernel_launch(void* const* d_in, const int* in_sizes, int n_in,
                              void* d_out, int out_size, void* d_ws, size_t ws_size,
                              hipStream_t stream) {
    const float* h          = (const float*)d_in[0];
    const int*   edge_index = (const int*)d_in[1];
    const float* edge_attr  = (const float*)d_in[2];
    const void*  reducible  = d_in[3];
    const float* red_W      = (const float*)d_in[4];
    const float* red_att_src= (const float*)d_in[5];
    const float* red_att_dst= (const float*)d_in[6];
    const float* red_W_edge = (const float*)d_in[7];
    const float* red_att_edge=(const float*)d_in[8];
    const float* red_W_res  = (const float*)d_in[9];
    const float* red_bias   = (const float*)d_in[10];
    const float* irr_W      = (const float*)d_in[11];
    const float* irr_att_src= (const float*)d_in[12];
    const float* irr_att_dst= (const float*)d_in[13];
    const float* irr_W_edge = (const float*)d_in[14];
    const float* irr_att_edge=(const float*)d_in[15];
    const float* irr_W_res  = (const float*)d_in[16];
    const float* irr_bias   = (const float*)d_in[17];

    const int N = in_sizes[0] / CDIM;
    const int E = in_sizes[1] / 2;
    const int* src = edge_index;
    const int* dst = edge_index + E;

    float* out = (float*)d_out;

    size_t cur = 0;
    auto alloc = [&](size_t bytes) { size_t p = cur; cur = (cur + bytes + 255) & ~(size_t)255; return p; };
    char* ws = (char*)d_ws;
    size_t o_xcat  = alloc((size_t)N * 512 * 2);   // bf16
    size_t o_hbf   = alloc((size_t)N * 128 * 2);   // bf16
    size_t o_bcat  = alloc(512 * 128 * 2);         // bf16 transposed
    size_t o_we    = alloc(256);
    size_t o_asr   = alloc((size_t)N * 4);
    size_t o_adr   = alloc((size_t)N * 4);
    size_t o_asi   = alloc((size_t)N * 4);
    size_t o_adi   = alloc((size_t)N * 4);
    size_t o_flags = alloc(256);
    size_t o_cnt   = alloc((size_t)N * 4);
    size_t o_off   = alloc((size_t)(N + 1) * 4);
    size_t o_cur   = alloc((size_t)N * 4);
    size_t o_srcs  = alloc((size_t)E * 4);
    size_t o_ers   = alloc((size_t)E * 4);
    size_t o_eis   = alloc((size_t)E * 4);
    if (cur > ws_size) return;

    ushort* xcat = (ushort*)(ws + o_xcat);
    ushort* hbf  = (ushort*)(ws + o_hbf);
    ushort* bcat = (ushort*)(ws + o_bcat);
    float* we    = (float*)(ws + o_we);
    float* asr   = (float*)(ws + o_asr);
    float* adr   = (float*)(ws + o_adr);
    float* asi   = (float*)(ws + o_asi);
    float* adi   = (float*)(ws + o_adi);
    int*   flags = (int*)(ws + o_flags);
    int*   cnt   = (int*)(ws + o_cnt);
    int*   offv  = (int*)(ws + o_off);
    int*   curs  = (int*)(ws + o_cur);
    int*   src_s = (int*)(ws + o_srcs);
    float* er_s  = (float*)(ws + o_ers);
    float* ei_s  = (float*)(ws + o_eis);

    hipMemsetAsync(flags, 0, 8, stream);
    hipMemsetAsync(cnt, 0, (size_t)N * 4, stream);

    int nwords = N / 4;
    flag_kernel<<<(nwords + 255) / 256, 256, 0, stream>>>((const uint*)reducible, nwords, flags);

    int n4 = N * 128 / 4;
    hconv_kernel<<<(n4 + 255) / 256, 256, 0, stream>>>(h, hbf, n4);
    bcat_kernel<<<(512 * 128 + 255) / 256, 256, 0, stream>>>(red_W, irr_W, red_W_res, irr_W_res, bcat);
    we_kernel<<<1, 32, 0, stream>>>(red_W_edge, red_att_edge, irr_W_edge, irr_att_edge, we);

    dim3 ggrid((N + 127) / 128, 4);
    gemm_mfma<<<ggrid, 256, 0, stream>>>(hbf, bcat, xcat, N);

    adots_kernel<<<(N + 3) / 4, 256, 0, stream>>>(xcat, red_att_src, red_att_dst,
                                                  irr_att_src, irr_att_dst, asr, adr, asi, adi, N);

    hist_kernel<<<(E + 255) / 256, 256, 0, stream>>>(dst, cnt, E);
    scan_kernel<<<1, 1024, 0, stream>>>(cnt, offv, curs, N);
    scatter_kernel<<<(E + 255) / 256, 256, 0, stream>>>(src, dst, edge_attr, we, curs,
                                                        src_s, er_s, ei_s, E);

    node_kernel<<<(N + 3) / 4, 256, 0, stream>>>(xcat, asr, adr, asi, adi,
                                                 reducible, flags, offv, src_s, er_s, ei_s,
                                                 red_bias, irr_bias, out, N);
}